// Round 1
// 11345.242 us; speedup vs baseline: 1.5348x; 1.5348x over previous
//
#include <hip/hip_runtime.h>

#define B_ 16
#define T_ 1024
#define D_ 128
#define H_ 1024
#define O_ 64
#define ALPHA_ 0.1f
#define LEAK_ 0.9f
#define GRID_SCAN 256
#define FLAG_STRIDE 32   // 128B per flag line

typedef float f32x4 __attribute__((ext_vector_type(4)));

// ---------------------------------------------------------------------------
// Kernel 1: P0[b][t][j] = ALPHA * (x[b,t,:] . W_in0[j,:] + b0[j])
// written INTO the states0 region of d_out. The scan reads P0 at (b,t,j) and
// overwrites the same address with tanh(v0) -> no extra buffer needed.
// ---------------------------------------------------------------------------
__global__ __launch_bounds__(256)
void p0_kernel(const float* __restrict__ X, const float* __restrict__ Win0,
               const float* __restrict__ b0, float* __restrict__ P)
{
    __shared__ float Xs[64][68];
    __shared__ float Ws[64][68];
    const int r0 = blockIdx.x * 64;
    const int j0 = blockIdx.y * 64;
    const int tid = threadIdx.x;
    const int ty = tid >> 4, tx = tid & 15;
    float acc[4][4] = {};

    for (int kc = 0; kc < D_; kc += 64) {
        for (int i = tid; i < 64 * 16; i += 256) {   // 64 rows x 16 float4
            int row = i >> 4, c = i & 15;
            *(float4*)&Xs[row][c * 4] =
                *(const float4*)&X[(size_t)(r0 + row) * D_ + kc + c * 4];
            *(float4*)&Ws[row][c * 4] =
                *(const float4*)&Win0[(size_t)(j0 + row) * D_ + kc + c * 4];
        }
        __syncthreads();
        #pragma unroll 4
        for (int k = 0; k < 64; k += 4) {
            float4 xr[4], wv[4];
            #pragma unroll
            for (int i = 0; i < 4; ++i) {
                xr[i] = *(const float4*)&Xs[ty * 4 + i][k];
                wv[i] = *(const float4*)&Ws[tx * 4 + i][k];
            }
            #pragma unroll
            for (int i = 0; i < 4; ++i)
                #pragma unroll
                for (int j = 0; j < 4; ++j) {
                    acc[i][j] = fmaf(xr[i].x, wv[j].x, acc[i][j]);
                    acc[i][j] = fmaf(xr[i].y, wv[j].y, acc[i][j]);
                    acc[i][j] = fmaf(xr[i].z, wv[j].z, acc[i][j]);
                    acc[i][j] = fmaf(xr[i].w, wv[j].w, acc[i][j]);
                }
        }
        __syncthreads();
    }
    #pragma unroll
    for (int i = 0; i < 4; ++i) {
        size_t r = (size_t)(r0 + ty * 4 + i);
        #pragma unroll
        for (int j = 0; j < 4; ++j) {
            int jj = j0 + tx * 4 + j;
            P[r * H_ + jj] = ALPHA_ * (acc[i][j] + b0[jj]);
        }
    }
}

// ---------------------------------------------------------------------------
// Kernel 2: fused 2-layer scan.
//
// Coherence redesign vs previous version (which spent ~90% of each 16.85us
// iteration in wbl2-fence / inv-fence / cold-refill / barrier):
//   * state writes  -> agent-scope relaxed atomic stores (write-through to
//     LLC; L2 never holds dirty scan state => no buffer_wbl2 release fence)
//   * state reads   -> inline-asm global_load_dwordx4 sc0 sc1 (bypass the
//     stale L1/L2, read the coherent LLC directly => no buffer_inv acquire
//     fence). P0 ("pval") is immutable during the scan => regular cached load.
//   * flag store    -> __ATOMIC_RELEASE agent store (formal release over a
//     CLEAN L2 = cheap); poll stays relaxed; the data loads are volatile asm
//     so they cannot be hoisted above the poll loop.
//   * loads software-pipelined in 4 bi-groups with counted vmcnt(16/16/8/0)
//     + sched_barrier(0) after each waitcnt (rule #18: hipcc hoists reg-only
//     FMAs past asm waitcnts without it).
// ---------------------------------------------------------------------------
#define LDX4(dst, p) \
    asm volatile("global_load_dwordx4 %0, %1, off sc0 sc1" : "=v"(dst) : "v"(p))
#define VMWAIT(n) asm volatile("s_waitcnt vmcnt(" #n ")" ::: "memory")
#define SB0 __builtin_amdgcn_sched_barrier(0)

#define ISSUE_AB(g) do {                                                   \
    const float* pa_ = sa + (size_t)(g) * BT;                              \
    const float* pb_ = sb + (size_t)(g) * BT;                              \
    LDX4(A[g][0], pa_);      LDX4(A[g][1], pa_ + 4);                       \
    LDX4(A[g][2], pa_ + 8);  LDX4(A[g][3], pa_ + 12);                      \
    LDX4(Bv[g][0], pb_);     LDX4(Bv[g][1], pb_ + 4);                      \
    LDX4(Bv[g][2], pb_ + 8); LDX4(Bv[g][3], pb_ + 12);                     \
} while (0)

#define ISSUE_A(g) do {                                                    \
    const float* pa_ = sa + (size_t)(g) * BT;                              \
    LDX4(A[g][0], pa_);      LDX4(A[g][1], pa_ + 4);                       \
    LDX4(A[g][2], pa_ + 8);  LDX4(A[g][3], pa_ + 12);                      \
} while (0)

#define FMA3(g) do {                                                       \
    _Pragma("unroll")                                                      \
    for (int m_ = 0; m_ < 4; ++m_) {                                       \
        _Pragma("unroll")                                                  \
        for (int c_ = 0; c_ < 4; ++c_) {                                   \
            const int kk_ = m_ * 4 + c_;                                   \
            const float xa_ = A[g][m_][c_];                                \
            const float xb_ = Bv[g][m_][c_];                               \
            _Pragma("unroll")                                              \
            for (int j_ = 0; j_ < 4; ++j_) {                               \
                ar0[(g)*4+j_] = fmaf(xa_, wr0[j_][kk_], ar0[(g)*4+j_]);    \
                ai1[(g)*4+j_] = fmaf(xa_, wi1[j_][kk_], ai1[(g)*4+j_]);    \
                ar1[(g)*4+j_] = fmaf(xb_, wr1[j_][kk_], ar1[(g)*4+j_]);    \
            }                                                              \
        }                                                                  \
    }                                                                      \
} while (0)

#define FMA2(g) do {                                                       \
    _Pragma("unroll")                                                      \
    for (int m_ = 0; m_ < 4; ++m_) {                                       \
        _Pragma("unroll")                                                  \
        for (int c_ = 0; c_ < 4; ++c_) {                                   \
            const int kk_ = m_ * 4 + c_;                                   \
            const float xa_ = A[g][m_][c_];                                \
            _Pragma("unroll")                                              \
            for (int j_ = 0; j_ < 4; ++j_) {                               \
                ar0[(g)*4+j_] = fmaf(xa_, wr0[j_][kk_], ar0[(g)*4+j_]);    \
                ai1[(g)*4+j_] = fmaf(xa_, wi1[j_][kk_], ai1[(g)*4+j_]);    \
            }                                                              \
        }                                                                  \
    }                                                                      \
} while (0)

__global__ __launch_bounds__(256, 1)
void scan_kernel(const float* __restrict__ Wr0,
                 const float* __restrict__ Wi1,
                 const float* __restrict__ Wr1,
                 const float* __restrict__ b1,
                 float* __restrict__ states0,   // pre-filled with P0
                 float* __restrict__ states1,
                 unsigned int* __restrict__ flags)
{
    const int tid  = threadIdx.x;
    const int blk  = blockIdx.x;
    const int jg   = blk & 127;     // 128 j-groups of 8
    const int bg   = blk >> 7;      // 2 batch-groups of 8
    const int lane = tid & 63;
    const int w    = tid >> 6;
    const int tile = lane & 3;
    const int kl   = lane >> 2;
    const int bh   = tile & 1;
    const int jh   = tile >> 1;
    const int ks   = w * 16 + kl;   // 0..63
    const int k0   = ks << 4;       // 16-wide k slice
    const int jbase = jg * 8 + jh * 4;
    const int bbase = bg * 8 + bh * 4;
    const size_t BT = (size_t)T_ * H_;

    // ---- pin weights in registers: [4 j][16 k] per matrix ----
    float wr0[4][16], wi1[4][16], wr1[4][16];
    #pragma unroll
    for (int j = 0; j < 4; ++j) {
        const float* p0 = Wr0 + (size_t)(jbase + j) * H_ + k0;
        const float* p1 = Wi1 + (size_t)(jbase + j) * H_ + k0;
        const float* p2 = Wr1 + (size_t)(jbase + j) * H_ + k0;
        #pragma unroll
        for (int m = 0; m < 4; ++m) {
            *(float4*)&wr0[j][m * 4] = ((const float4*)p0)[m];
            *(float4*)&wi1[j][m * 4] = ((const float4*)p1)[m];
            *(float4*)&wr1[j][m * 4] = ((const float4*)p2)[m];
        }
    }

    // ---- owners: tid 0..63 own layer0 outputs, tid 64..127 layer1 ----
    const int o      = tid & 63;
    const int b_loc  = o >> 3, j_loc = o & 7;
    const int gb     = bg * 8 + b_loc;
    const int gj     = jg * 8 + j_loc;
    const int otile  = (j_loc >> 2) * 2 + (b_loc >> 2);
    const int oa     = (b_loc & 3) * 4 + (j_loc & 3);
    float v0 = 0.f, v1 = 0.f;
    const float b1v = b1[gj];

    __shared__ float red[3][4][4][16];   // [matvec][wave][tile][acc]

    unsigned* myflag   = flags + (size_t)blk * FLAG_STRIDE;
    unsigned* pollflag = flags + (size_t)tid * FLAG_STRIDE;

    for (int it = 0; it <= T_; ++it) {
        // early P0 load for layer0 owners. P0 is written before the scan
        // launches and only overwritten by THIS thread later this iteration,
        // so a regular cached load is safe (never stale).
        float pval = 0.f;
        size_t oidx0 = 0;
        if (tid < 64 && it < T_) {
            oidx0 = (size_t)gb * BT + (size_t)it * H_ + gj;
            pval = states0[oidx0];
        }

        float ar0[16], ai1[16], ar1[16];
        #pragma unroll
        for (int a = 0; a < 16; ++a) { ar0[a] = 0.f; ai1[a] = 0.f; ar1[a] = 0.f; }

        if (it >= 2) {
            f32x4 A[4][4], Bv[4][4];
            const float* sa = states0 + (size_t)bbase * BT + (size_t)(it - 1) * H_ + k0;
            const float* sb = states1 + (size_t)bbase * BT + (size_t)(it - 2) * H_ + k0;
            // pipeline: 3 groups in flight, peel one per FMA block
            ISSUE_AB(0); ISSUE_AB(1); ISSUE_AB(2);
            VMWAIT(16); SB0;            // group0 (+pval) landed
            FMA3(0);
            ISSUE_AB(3);
            VMWAIT(16); SB0;            // group1 landed
            FMA3(1);
            VMWAIT(8); SB0;             // group2 landed
            FMA3(2);
            VMWAIT(0); SB0;             // group3 landed
            FMA3(3);
        } else if (it == 1) {
            f32x4 A[4][4];
            const float* sa = states0 + (size_t)bbase * BT + k0;   // t = 0
            ISSUE_A(0); ISSUE_A(1); ISSUE_A(2); ISSUE_A(3);
            VMWAIT(0); SB0;
            FMA2(0); FMA2(1); FMA2(2); FMA2(3);   // ar1 stays 0 (fr1[-1]=0)
        }

        // in-wave reduction over kl (lane bits 2..5)
        #pragma unroll
        for (int mask = 4; mask < 64; mask <<= 1)
            #pragma unroll
            for (int a = 0; a < 16; ++a) {
                ar0[a] += __shfl_xor(ar0[a], mask);
                ai1[a] += __shfl_xor(ai1[a], mask);
                ar1[a] += __shfl_xor(ar1[a], mask);
            }
        if (lane < 4) {
            #pragma unroll
            for (int a = 0; a < 16; ++a) {
                red[0][w][lane][a] = ar0[a];
                red[1][w][lane][a] = ai1[a];
                red[2][w][lane][a] = ar1[a];
            }
        }
        __syncthreads();

        if (tid < 64) {
            if (it < T_) {
                float s = red[0][0][otile][oa] + red[0][1][otile][oa]
                        + red[0][2][otile][oa] + red[0][3][otile][oa];
                v0 = LEAK_ * v0 + pval + ALPHA_ * s;
                float fr = tanhf(v0);
                // write-through to LLC (agent scope): no dirty L2 state
                __hip_atomic_store(&states0[oidx0], fr, __ATOMIC_RELAXED,
                                   __HIP_MEMORY_SCOPE_AGENT);
            }
        } else if (tid < 128) {
            if (it >= 1) {
                float s1 = red[1][0][otile][oa] + red[1][1][otile][oa]
                         + red[1][2][otile][oa] + red[1][3][otile][oa];
                float s2 = red[2][0][otile][oa] + red[2][1][otile][oa]
                         + red[2][2][otile][oa] + red[2][3][otile][oa];
                v1 = LEAK_ * v1 + ALPHA_ * (s1 + s2 + b1v);
                float fr = tanhf(v1);
                __hip_atomic_store(&states1[(size_t)gb * BT + (size_t)(it - 1) * H_ + gj],
                                   fr, __ATOMIC_RELAXED, __HIP_MEMORY_SCOPE_AGENT);
            }
        }

        if (it < T_) {
            // ---- grid barrier: distributed flags, no L2 fences ----
            __syncthreads();   // drains all waves' stores (vmcnt0 @ barrier)
            const unsigned tgt = (unsigned)(it + 1);
            if (tid == 0) {
                // release store: orders the (already write-through) state
                // stores before the flag becomes visible at the LLC.
                __hip_atomic_store(myflag, tgt, __ATOMIC_RELEASE,
                                   __HIP_MEMORY_SCOPE_AGENT);
            }
            // each thread polls its own block's flag line (256 distinct lines)
            while (__hip_atomic_load(pollflag, __ATOMIC_RELAXED,
                                     __HIP_MEMORY_SCOPE_AGENT) < tgt)
                __builtin_amdgcn_s_sleep(2);
            __syncthreads();
            // no acquire fence: next iteration's state reads bypass L1/L2
            // (sc0 sc1) and read the coherent LLC directly.
        }
    }
}

// ---------------------------------------------------------------------------
// Kernel 3: out[r][o] = states1[r,:] . W_out[o,:] + b_out[o],  r = b*T+t
// ---------------------------------------------------------------------------
__global__ __launch_bounds__(256)
void out_kernel(const float* __restrict__ S1, const float* __restrict__ Wout,
                const float* __restrict__ bout, float* __restrict__ Out)
{
    __shared__ float Ss[64][36];
    __shared__ float Ws[64][36];
    const int r0 = blockIdx.x * 64;
    const int tid = threadIdx.x;
    const int ty = tid >> 4, tx = tid & 15;
    float acc[4][4] = {};

    for (int kc = 0; kc < H_; kc += 32) {
        for (int i = tid; i < 64 * 8; i += 256) {   // 64 rows x 8 float4
            int row = i >> 3, c = i & 7;
            *(float4*)&Ss[row][c * 4] =
                *(const float4*)&S1[(size_t)(r0 + row) * H_ + kc + c * 4];
            *(float4*)&Ws[row][c * 4] =
                *(const float4*)&Wout[(size_t)row * H_ + kc + c * 4];
        }
        __syncthreads();
        #pragma unroll 2
        for (int k = 0; k < 32; k += 4) {
            float4 xr[4], wv[4];
            #pragma unroll
            for (int i = 0; i < 4; ++i) {
                xr[i] = *(const float4*)&Ss[ty * 4 + i][k];
                wv[i] = *(const float4*)&Ws[tx * 4 + i][k];
            }
            #pragma unroll
            for (int i = 0; i < 4; ++i)
                #pragma unroll
                for (int j = 0; j < 4; ++j) {
                    acc[i][j] = fmaf(xr[i].x, wv[j].x, acc[i][j]);
                    acc[i][j] = fmaf(xr[i].y, wv[j].y, acc[i][j]);
                    acc[i][j] = fmaf(xr[i].z, wv[j].z, acc[i][j]);
                    acc[i][j] = fmaf(xr[i].w, wv[j].w, acc[i][j]);
                }
        }
        __syncthreads();
    }
    #pragma unroll
    for (int i = 0; i < 4; ++i) {
        size_t r = (size_t)(r0 + ty * 4 + i);
        #pragma unroll
        for (int j = 0; j < 4; ++j) {
            int oo = tx * 4 + j;
            Out[r * O_ + oo] = acc[i][j] + bout[oo];
        }
    }
}

// ---------------------------------------------------------------------------
extern "C" void kernel_launch(void* const* d_in, const int* in_sizes, int n_in,
                              void* d_out, int out_size, void* d_ws, size_t ws_size,
                              hipStream_t stream)
{
    (void)in_sizes; (void)n_in; (void)out_size; (void)ws_size;

    const float* x    = (const float*)d_in[0];
    const float* Win0 = (const float*)d_in[1];
    const float* Wr0  = (const float*)d_in[2];
    const float* b0   = (const float*)d_in[3];
    const float* Wi1  = (const float*)d_in[4];
    const float* Wr1  = (const float*)d_in[5];
    const float* b1   = (const float*)d_in[6];
    const float* Wout = (const float*)d_in[7];
    const float* bout = (const float*)d_in[8];

    float* out     = (float*)d_out;
    float* states0 = out + (size_t)B_ * T_ * O_;
    float* states1 = states0 + (size_t)B_ * T_ * H_;

    unsigned* flags = (unsigned*)d_ws;   // 256 flags, 128B apart = 32KB

    // zero flag lines (ws is poisoned 0xAA before every call)
    hipMemsetAsync(d_ws, 0, GRID_SCAN * FLAG_STRIDE * sizeof(unsigned), stream);

    // P0 -> states0 region
    p0_kernel<<<dim3(B_ * T_ / 64, H_ / 64), 256, 0, stream>>>(x, Win0, b0, states0);

    // fused scan
    scan_kernel<<<dim3(GRID_SCAN), dim3(256), 0, stream>>>(
        Wr0, Wi1, Wr1, b1, states0, states1, flags);

    // readout
    out_kernel<<<dim3(B_ * T_ / 64), 256, 0, stream>>>(states1, Wout, bout, out);
}